// Round 1
// baseline (1272.439 us; speedup 1.0000x reference)
//
#include <hip/hip_runtime.h>
#include <float.h>

#define K_CLUST 10000
#define DIM     128
#define N_SAMP  16384           // 16*32*32
#define MT      16              // samples per block
#define KPT     4               // k columns per thread per chunk
#define BLOCK   256
// chunk = BLOCK*KPT = 1024 k's; 10 chunks cover K=10000

// ---------------- Kernel A: msq[k] = ||m_k||^2, zero diff slot ----------------
__global__ void prep_kernel(const float* __restrict__ m, float* __restrict__ msq,
                            float* __restrict__ diff_out) {
    int k = blockIdx.x * blockDim.x + threadIdx.x;
    if (blockIdx.x == 0 && threadIdx.x == 0) *diff_out = 0.0f;
    if (k < K_CLUST) {
        float s = 0.f;
        #pragma unroll 8
        for (int d = 0; d < DIM; ++d) {
            float v = m[d * K_CLUST + k];   // coalesced across k
            s += v * v;
        }
        msq[k] = s;
    }
}

// ---------------- Kernel B: argmax_k ( msq[k] - 2 * x_s . m_k ) ----------------
__global__ __launch_bounds__(BLOCK) void argmax_kernel(
        const float* __restrict__ x, const float* __restrict__ m,
        const float* __restrict__ msq, float* __restrict__ idx_f,
        int* __restrict__ idx_i) {
    __shared__ float4 xs[MT][DIM / 4];     // 8 KB sample tile
    __shared__ float  sc[MT][BLOCK];       // 16 KB reduce scores
    __shared__ int    ki[MT][BLOCK];       // 16 KB reduce indices

    const int tid = threadIdx.x;
    const int s0  = blockIdx.x * MT;       // first sample of this block

    // stage x tile (MT*DIM floats = 512 float4)
    const float4* x4 = (const float4*)(x + (size_t)s0 * DIM);
    float4* xs_flat = &xs[0][0];
    for (int i = tid; i < MT * DIM / 4; i += BLOCK) xs_flat[i] = x4[i];
    __syncthreads();

    float best[MT];
    int   bestk[MT];
    #pragma unroll
    for (int s = 0; s < MT; ++s) { best[s] = -FLT_MAX; bestk[s] = K_CLUST; }

    for (int kbase = 0; kbase < K_CLUST; kbase += BLOCK * KPT) {
        int  kk[KPT];
        bool valid[KPT];
        #pragma unroll
        for (int i = 0; i < KPT; ++i) {
            int k = kbase + tid + i * BLOCK;
            valid[i] = (k < K_CLUST);
            kk[i] = valid[i] ? k : (K_CLUST - 1);   // clamp: no OOB loads
        }

        float acc[MT][KPT];
        #pragma unroll
        for (int s = 0; s < MT; ++s)
            #pragma unroll
            for (int i = 0; i < KPT; ++i) acc[s][i] = 0.f;

        for (int d4 = 0; d4 < DIM / 4; ++d4) {
            float mv[4][KPT];
            #pragma unroll
            for (int j = 0; j < 4; ++j)
                #pragma unroll
                for (int i = 0; i < KPT; ++i)
                    mv[j][i] = m[(size_t)(d4 * 4 + j) * K_CLUST + kk[i]]; // coalesced across tid
            #pragma unroll
            for (int s = 0; s < MT; ++s) {
                float4 xv = xs[s][d4];     // wave-uniform address -> LDS broadcast
                #pragma unroll
                for (int i = 0; i < KPT; ++i)
                    acc[s][i] += xv.x * mv[0][i] + xv.y * mv[1][i]
                               + xv.z * mv[2][i] + xv.w * mv[3][i];
            }
        }

        // per-thread running argmax; k increases with i, so strict '>' keeps first index
        #pragma unroll
        for (int i = 0; i < KPT; ++i) {
            if (!valid[i]) continue;
            float mq = msq[kk[i]];
            #pragma unroll
            for (int s = 0; s < MT; ++s) {
                float score = mq - 2.f * acc[s][i];
                if (score > best[s]) { best[s] = score; bestk[s] = kk[i]; }
            }
        }
    }

    // cross-thread argmax reduce: 16 threads per sample
    #pragma unroll
    for (int s = 0; s < MT; ++s) { sc[s][tid] = best[s]; ki[s][tid] = bestk[s]; }
    __syncthreads();

    const int s = tid >> 4, j = tid & 15;
    float b = -FLT_MAX; int bk = K_CLUST;
    for (int e = j; e < BLOCK; e += 16) {
        float v = sc[s][e]; int kv = ki[s][e];
        if (v > b || (v == b && kv < bk)) { b = v; bk = kv; }
    }
    #pragma unroll
    for (int off = 8; off; off >>= 1) {
        float ov = __shfl_down(b, off);
        int   ok = __shfl_down(bk, off);
        if (ov > b || (ov == b && ok < bk)) { b = ov; bk = ok; }
    }
    if (j == 0) { idx_i[s0 + s] = bk; idx_f[s0 + s] = (float)bk; }
}

// ---------------- Kernel C: gather quantize, MSE ----------------
__global__ void quant_kernel(const float* __restrict__ x, const float* __restrict__ m,
                             const int* __restrict__ idx_i, float* __restrict__ qout,
                             float* __restrict__ diff_out) {
    int g = blockIdx.x * 256 + threadIdx.x;     // one thread per (sample, d)
    int samp = g >> 7;
    int d    = g & 127;
    int idx  = idx_i[samp];
    float q  = m[(size_t)d * K_CLUST + idx];
    float xv = x[g];
    qout[g] = q;
    float dd = xv - q; dd *= dd;
    #pragma unroll
    for (int off = 32; off; off >>= 1) dd += __shfl_down(dd, off);
    __shared__ float wsum[4];
    int lane = threadIdx.x & 63, wv = threadIdx.x >> 6;
    if (lane == 0) wsum[wv] = dd;
    __syncthreads();
    if (threadIdx.x == 0) {
        float t = wsum[0] + wsum[1] + wsum[2] + wsum[3];
        atomicAdd(diff_out, t * (1.0f / ((float)N_SAMP * (float)DIM)));
    }
}

extern "C" void kernel_launch(void* const* d_in, const int* in_sizes, int n_in,
                              void* d_out, int out_size, void* d_ws, size_t ws_size,
                              hipStream_t stream) {
    const float* x = (const float*)d_in[0];          // [16,32,32,128]
    const float* m = (const float*)d_in[1];          // [128,10000]
    float* out    = (float*)d_out;
    float* quant  = out;                              // 2,097,152 floats
    float* idx_f  = out + (size_t)N_SAMP * DIM;       // 16,384 floats (index as float)
    float* diff   = out + (size_t)N_SAMP * DIM + N_SAMP; // 1 float
    float* msq    = (float*)d_ws;                     // 10,000 floats
    int*   idx_i  = (int*)((char*)d_ws + 40960);      // 16,384 ints

    prep_kernel<<<(K_CLUST + 255) / 256, 256, 0, stream>>>(m, msq, diff);
    argmax_kernel<<<N_SAMP / MT, BLOCK, 0, stream>>>(x, m, msq, idx_f, idx_i);
    quant_kernel<<<(N_SAMP * DIM) / 256, 256, 0, stream>>>(x, m, idx_i, quant, diff);
}

// Round 2
// 701.220 us; speedup vs baseline: 1.8146x; 1.8146x over previous
//
#include <hip/hip_runtime.h>
#include <float.h>

#define K_CLUST 10000
#define DIM     128
#define N_SAMP  16384           // 16*32*32
#define MT      16              // samples per block
#define KPT     4               // consecutive k columns per thread per chunk
#define BLOCK   256
#define KSPLIT  2
#define HALF_K  5000            // k range per split
#define CHUNK   (BLOCK * KPT)   // 1024 k per chunk
#define NCHUNK  5               // ceil(5000/1024)

// ---------------- Kernel A: msq[k] = ||m_k||^2, zero diff slot ----------------
__global__ void prep_kernel(const float* __restrict__ m, float* __restrict__ msq,
                            float* __restrict__ diff_out) {
    int k = blockIdx.x * blockDim.x + threadIdx.x;
    if (blockIdx.x == 0 && threadIdx.x == 0) *diff_out = 0.0f;
    if (k < K_CLUST) {
        float s = 0.f;
        #pragma unroll 8
        for (int d = 0; d < DIM; ++d) {
            float v = m[d * K_CLUST + k];   // coalesced across k
            s += v * v;
        }
        msq[k] = s;
    }
}

// ------- Kernel B: per (sample-tile, K-half) argmax of msq[k] - 2 x.m_k -------
// LDS kept to ~8.7 KB so occupancy is VGPR/grid bound, not LDS bound.
__global__ __launch_bounds__(BLOCK) void argmax_kernel(
        const float* __restrict__ x, const float* __restrict__ m,
        const float* __restrict__ msq,
        float* __restrict__ cscore, int* __restrict__ cidx) {
    __shared__ float4 xs[MT][DIM / 4];   // 8 KB sample tile
    __shared__ float  red_s[4][MT];      // 256 B cross-wave scores
    __shared__ int    red_k[4][MT];      // 256 B cross-wave indices

    const int tid    = threadIdx.x;
    const int half   = blockIdx.x & 1;            // which K half
    const int tile   = blockIdx.x >> 1;
    const int s0     = tile * MT;
    const int kstart = half * HALF_K;
    const int kend   = kstart + HALF_K;           // 5000 or 10000

    // stage x tile (MT*DIM floats = 512 float4)
    const float4* x4 = (const float4*)(x + (size_t)s0 * DIM);
    float4* xs_flat = &xs[0][0];
    for (int i = tid; i < MT * DIM / 4; i += BLOCK) xs_flat[i] = x4[i];
    __syncthreads();

    float best[MT];
    int   bestk[MT];
    #pragma unroll
    for (int s = 0; s < MT; ++s) { best[s] = -FLT_MAX; bestk[s] = 0x7fffffff; }

    for (int c = 0; c < NCHUNK; ++c) {
        int k0  = kstart + c * CHUNK + KPT * tid;   // 4 consecutive k's, 16B aligned
        int k0c = min(k0, K_CLUST - KPT);           // clamp: duplicates are bit-identical
        const float* mp = m + k0c;

        float acc[MT][KPT];
        #pragma unroll
        for (int s = 0; s < MT; ++s)
            #pragma unroll
            for (int i = 0; i < KPT; ++i) acc[s][i] = 0.f;

        for (int d4 = 0; d4 < DIM / 4; ++d4) {
            float mvv[4][KPT];                      // mvv[j][i] = m[d4*4+j][k0c+i]
            #pragma unroll
            for (int j = 0; j < 4; ++j) {
                float4 v = *(const float4*)(mp + (size_t)(d4 * 4 + j) * K_CLUST);
                mvv[j][0] = v.x; mvv[j][1] = v.y; mvv[j][2] = v.z; mvv[j][3] = v.w;
            }
            #pragma unroll
            for (int s = 0; s < MT; ++s) {
                float4 xv = xs[s][d4];              // wave-uniform -> LDS broadcast
                #pragma unroll
                for (int i = 0; i < KPT; ++i) {
                    acc[s][i] = fmaf(xv.x, mvv[0][i], acc[s][i]);
                    acc[s][i] = fmaf(xv.y, mvv[1][i], acc[s][i]);
                    acc[s][i] = fmaf(xv.z, mvv[2][i], acc[s][i]);
                    acc[s][i] = fmaf(xv.w, mvv[3][i], acc[s][i]);
                }
            }
        }

        float4 mq4 = *(const float4*)(msq + k0c);
        float mqa[KPT] = {mq4.x, mq4.y, mq4.z, mq4.w};
        #pragma unroll
        for (int i = 0; i < KPT; ++i) {
            int k = k0c + i;
            if (k < kend) {                         // half0 gates k<5000; dup k's tie out
                #pragma unroll
                for (int s = 0; s < MT; ++s) {
                    float score = mqa[i] - 2.f * acc[s][i];
                    // ascending k within thread: strict '>' keeps lowest k
                    if (score > best[s]) { best[s] = score; bestk[s] = k; }
                }
            }
        }
    }

    // wave shuffle argmax (prefer lower k on tie), then 4-wave LDS merge
    const int lane = tid & 63, wv = tid >> 6;
    #pragma unroll
    for (int s = 0; s < MT; ++s) {
        float b = best[s]; int bk = bestk[s];
        #pragma unroll
        for (int off = 32; off; off >>= 1) {
            float ov = __shfl_down(b, off);
            int   ok = __shfl_down(bk, off);
            if (ov > b || (ov == b && ok < bk)) { b = ov; bk = ok; }
        }
        if (lane == 0) { red_s[wv][s] = b; red_k[wv][s] = bk; }
    }
    __syncthreads();
    if (tid < MT) {
        float b = red_s[0][tid]; int bk = red_k[0][tid];
        #pragma unroll
        for (int w = 1; w < 4; ++w) {
            float ov = red_s[w][tid]; int ok = red_k[w][tid];
            if (ov > b || (ov == b && ok < bk)) { b = ov; bk = ok; }
        }
        cscore[half * N_SAMP + s0 + tid] = b;
        cidx  [half * N_SAMP + s0 + tid] = bk;
    }
}

// -------- Kernel C: merge K-halves, gather quantize, write index, MSE --------
__global__ void quant_kernel(const float* __restrict__ x, const float* __restrict__ m,
                             const float* __restrict__ cscore, const int* __restrict__ cidx,
                             float* __restrict__ qout, float* __restrict__ idx_f,
                             float* __restrict__ diff_out) {
    int g = blockIdx.x * 256 + threadIdx.x;     // one thread per (sample, d)
    int samp = g >> 7;
    int d    = g & 127;
    float sA = cscore[samp];
    float sB = cscore[N_SAMP + samp];
    int   iA = cidx[samp];
    int   iB = cidx[N_SAMP + samp];
    int  idx = (sB > sA) ? iB : iA;             // tie -> half0 (lower k)
    float q  = m[(size_t)d * K_CLUST + idx];
    float xv = x[g];
    qout[g] = q;
    if (d == 0) idx_f[samp] = (float)idx;
    float dd = xv - q; dd *= dd;
    #pragma unroll
    for (int off = 32; off; off >>= 1) dd += __shfl_down(dd, off);
    __shared__ float wsum[4];
    int lane = threadIdx.x & 63, wv = threadIdx.x >> 6;
    if (lane == 0) wsum[wv] = dd;
    __syncthreads();
    if (threadIdx.x == 0) {
        float t = wsum[0] + wsum[1] + wsum[2] + wsum[3];
        atomicAdd(diff_out, t * (1.0f / ((float)N_SAMP * (float)DIM)));
    }
}

extern "C" void kernel_launch(void* const* d_in, const int* in_sizes, int n_in,
                              void* d_out, int out_size, void* d_ws, size_t ws_size,
                              hipStream_t stream) {
    const float* x = (const float*)d_in[0];          // [16,32,32,128]
    const float* m = (const float*)d_in[1];          // [128,10000]
    float* out    = (float*)d_out;
    float* quant  = out;                              // 2,097,152 floats
    float* idx_f  = out + (size_t)N_SAMP * DIM;       // 16,384 floats
    float* diff   = out + (size_t)N_SAMP * DIM + N_SAMP; // 1 float

    float* msq    = (float*)d_ws;                                 // 10,000 floats
    float* cscore = (float*)((char*)d_ws + 40960);                // 2*16,384 floats
    int*   cidx   = (int*)  ((char*)d_ws + 40960 + 131072);       // 2*16,384 ints

    prep_kernel<<<(K_CLUST + 255) / 256, 256, 0, stream>>>(m, msq, diff);
    argmax_kernel<<<(N_SAMP / MT) * KSPLIT, BLOCK, 0, stream>>>(x, m, msq, cscore, cidx);
    quant_kernel<<<(N_SAMP * DIM) / 256, 256, 0, stream>>>(x, m, cscore, cidx,
                                                           quant, idx_f, diff);
}

// Round 3
// 537.460 us; speedup vs baseline: 2.3675x; 1.3047x over previous
//
#include <hip/hip_runtime.h>
#include <float.h>

#define K_CLUST 10000
#define DIM     128
#define N_SAMP  16384           // 16*32*32
#define MT      16              // samples per block
#define KPT     4               // consecutive k columns per thread per chunk
#define BLOCK   256
#define KSPLIT  2
#define HALF_K  5000
#define CHUNK   (BLOCK * KPT)   // 1024 k per chunk
#define NCHUNK  5               // ceil(5000/1024)

// ---- Kernel A: msq[k] = ||m_k||^2, mT = m^T [K,DIM], zero diff slot ----
__global__ __launch_bounds__(256) void prep_kernel(
        const float* __restrict__ m, float* __restrict__ msq,
        float* __restrict__ mT, float* __restrict__ diff_out) {
    __shared__ float tile[64][DIM + 1];   // +1 pad: conflict-free column writes
    __shared__ float psum[64][4];

    const int tid = threadIdx.x;
    const int kl  = tid & 63;             // consecutive tid -> consecutive k (coalesced)
    const int dg  = tid >> 6;             // d-group 0..3
    const int k0  = blockIdx.x * 64;
    const int k   = k0 + kl;

    float ss = 0.f;
    if (k < K_CLUST) {
        #pragma unroll 4
        for (int dd = 0; dd < 32; ++dd) {
            int d = dg * 32 + dd;
            float v = m[(size_t)d * K_CLUST + k];
            tile[kl][d] = v;
            ss = fmaf(v, v, ss);
        }
    }
    psum[kl][dg] = ss;
    __syncthreads();
    if (dg == 0 && k < K_CLUST)
        msq[k] = psum[kl][0] + psum[kl][1] + psum[kl][2] + psum[kl][3];

    // transpose write: thread -> row r, quarter p (32 floats); wave writes 8KB contiguous
    const int r = tid >> 2, p = tid & 3;
    if (k0 + r < K_CLUST) {
        float4* dst = (float4*)(mT + (size_t)(k0 + r) * DIM + p * 32);
        #pragma unroll
        for (int j = 0; j < 8; ++j) {
            float4 v;
            v.x = tile[r][p * 32 + 4 * j + 0];
            v.y = tile[r][p * 32 + 4 * j + 1];
            v.z = tile[r][p * 32 + 4 * j + 2];
            v.w = tile[r][p * 32 + 4 * j + 3];
            dst[j] = v;
        }
    }
    if (blockIdx.x == 0 && tid == 0) *diff_out = 0.f;
}

// ------- Kernel B: per (sample-tile, K-half) argmax of msq[k] - 2 x.m_k -------
// x is read with wave-uniform addresses -> compiler scalarizes to s_load (SGPRs);
// v_fmac_f32 takes the x operand from an SGPR. No LDS in the hot loop.
__global__ __launch_bounds__(BLOCK) void argmax_kernel(
        const float* __restrict__ x, const float* __restrict__ m,
        const float* __restrict__ msq,
        float* __restrict__ cscore, int* __restrict__ cidx) {
    __shared__ float red_s[4][MT];       // 256 B cross-wave scores
    __shared__ int   red_k[4][MT];       // 256 B cross-wave indices

    const int tid    = threadIdx.x;
    const int half   = blockIdx.x & 1;
    const int tile   = blockIdx.x >> 1;
    const int s0     = tile * MT;
    const int kstart = half * HALF_K;
    const int kend   = kstart + HALF_K;
    const float4* xp4 = (const float4*)(x + (size_t)s0 * DIM);  // block-uniform base

    float best[MT];
    int   bestk[MT];
    #pragma unroll
    for (int s = 0; s < MT; ++s) { best[s] = -FLT_MAX; bestk[s] = 0x7fffffff; }

    for (int c = 0; c < NCHUNK; ++c) {
        int k0  = kstart + c * CHUNK + KPT * tid;   // 4 consecutive k's, 16B aligned
        int k0c = min(k0, K_CLUST - KPT);           // clamp: dup scores tie out
        const float* mp = m + k0c;

        float acc[MT][KPT];
        #pragma unroll
        for (int s = 0; s < MT; ++s)
            #pragma unroll
            for (int i = 0; i < KPT; ++i) acc[s][i] = 0.f;

        for (int d4 = 0; d4 < DIM / 4; ++d4) {
            float mvv[4][KPT];                      // mvv[j][i] = m[d4*4+j][k0c+i]
            #pragma unroll
            for (int j = 0; j < 4; ++j) {
                float4 v = *(const float4*)(mp + (size_t)(d4 * 4 + j) * K_CLUST);
                mvv[j][0] = v.x; mvv[j][1] = v.y; mvv[j][2] = v.z; mvv[j][3] = v.w;
            }
            #pragma unroll
            for (int s = 0; s < MT; ++s) {
                float4 xv = xp4[s * (DIM / 4) + d4];  // uniform -> s_load_dwordx4
                #pragma unroll
                for (int i = 0; i < KPT; ++i) {
                    acc[s][i] = fmaf(xv.x, mvv[0][i], acc[s][i]);
                    acc[s][i] = fmaf(xv.y, mvv[1][i], acc[s][i]);
                    acc[s][i] = fmaf(xv.z, mvv[2][i], acc[s][i]);
                    acc[s][i] = fmaf(xv.w, mvv[3][i], acc[s][i]);
                }
            }
        }

        float4 mq4 = *(const float4*)(msq + k0c);
        float mqa[KPT] = {mq4.x, mq4.y, mq4.z, mq4.w};
        #pragma unroll
        for (int i = 0; i < KPT; ++i) {
            int k = k0c + i;
            if (k < kend) {                         // half-0 gates k<5000
                #pragma unroll
                for (int s = 0; s < MT; ++s) {
                    float score = mqa[i] - 2.f * acc[s][i];
                    // ascending k within thread: strict '>' keeps lowest k
                    if (score > best[s]) { best[s] = score; bestk[s] = k; }
                }
            }
        }
    }

    // wave shuffle argmax (prefer lower k on tie), then 4-wave LDS merge
    const int lane = tid & 63, wv = tid >> 6;
    #pragma unroll
    for (int s = 0; s < MT; ++s) {
        float b = best[s]; int bk = bestk[s];
        #pragma unroll
        for (int off = 32; off; off >>= 1) {
            float ov = __shfl_down(b, off);
            int   ok = __shfl_down(bk, off);
            if (ov > b || (ov == b && ok < bk)) { b = ov; bk = ok; }
        }
        if (lane == 0) { red_s[wv][s] = b; red_k[wv][s] = bk; }
    }
    __syncthreads();
    if (tid < MT) {
        float b = red_s[0][tid]; int bk = red_k[0][tid];
        #pragma unroll
        for (int w = 1; w < 4; ++w) {
            float ov = red_s[w][tid]; int ok = red_k[w][tid];
            if (ov > b || (ov == b && ok < bk)) { b = ov; bk = ok; }
        }
        cscore[half * N_SAMP + s0 + tid] = b;
        cidx  [half * N_SAMP + s0 + tid] = bk;
    }
}

// -- Kernel C: merge K-halves, coalesced gather from mT, write index, MSE --
__global__ void quant_kernel(const float* __restrict__ x, const float* __restrict__ mT,
                             const float* __restrict__ cscore, const int* __restrict__ cidx,
                             float* __restrict__ qout, float* __restrict__ idx_f,
                             float* __restrict__ diff_out) {
    int g = blockIdx.x * 256 + threadIdx.x;     // one thread per (sample, d4)
    int samp = g >> 5;
    int d4   = g & 31;
    float sA = cscore[samp];
    float sB = cscore[N_SAMP + samp];
    int   iA = cidx[samp];
    int   iB = cidx[N_SAMP + samp];
    int  idx = (sB > sA) ? iB : iA;             // tie -> half0 (lower k)
    float4 q  = ((const float4*)mT)[(size_t)idx * (DIM / 4) + d4];  // coalesced row
    float4 xv = ((const float4*)x)[g];
    ((float4*)qout)[g] = q;
    if (d4 == 0) idx_f[samp] = (float)idx;
    float ax = xv.x - q.x, ay = xv.y - q.y, az = xv.z - q.z, aw = xv.w - q.w;
    float dd = ax * ax + ay * ay + az * az + aw * aw;
    #pragma unroll
    for (int off = 32; off; off >>= 1) dd += __shfl_down(dd, off);
    __shared__ float wsum[4];
    int lane = threadIdx.x & 63, wv = threadIdx.x >> 6;
    if (lane == 0) wsum[wv] = dd;
    __syncthreads();
    if (threadIdx.x == 0) {
        float t = wsum[0] + wsum[1] + wsum[2] + wsum[3];
        atomicAdd(diff_out, t * (1.0f / ((float)N_SAMP * (float)DIM)));
    }
}

extern "C" void kernel_launch(void* const* d_in, const int* in_sizes, int n_in,
                              void* d_out, int out_size, void* d_ws, size_t ws_size,
                              hipStream_t stream) {
    const float* x = (const float*)d_in[0];          // [16,32,32,128]
    const float* m = (const float*)d_in[1];          // [128,10000]
    float* out    = (float*)d_out;
    float* quant  = out;                              // 2,097,152 floats
    float* idx_f  = out + (size_t)N_SAMP * DIM;       // 16,384 floats
    float* diff   = out + (size_t)N_SAMP * DIM + N_SAMP; // 1 float

    char* ws = (char*)d_ws;
    float* msq    = (float*)ws;                       // 10,000 f   (offset 0)
    float* cscore = (float*)(ws + 40960);             // 32,768 f
    int*   cidx   = (int*)  (ws + 40960 + 131072);    // 32,768 i
    float* mT     = (float*)(ws + 40960 + 262144);    // 10,000*128 f = 5.12 MB

    prep_kernel<<<(K_CLUST + 63) / 64, 256, 0, stream>>>(m, msq, mT, diff);
    argmax_kernel<<<(N_SAMP / MT) * KSPLIT, BLOCK, 0, stream>>>(x, m, msq, cscore, cidx);
    quant_kernel<<<(N_SAMP * DIM / 4) / 256, 256, 0, stream>>>(x, mT, cscore, cidx,
                                                               quant, idx_f, diff);
}

// Round 4
// 208.012 us; speedup vs baseline: 6.1171x; 2.5838x over previous
//
#include <hip/hip_runtime.h>
#include <float.h>

#define K_CLUST 10000
#define K_PAD   10240           // 640 k-tiles of 16
#define DIM     128
#define N_SAMP  16384
#define KSPLIT  16
#define KT_PER  40              // 640 ktiles / 16 splits
#define CAP     16              // candidate list capacity per sample
#define MARGIN2 1.5f            // 2x worst-case f16 score error (~0.38) each side

typedef _Float16 half8  __attribute__((ext_vector_type(8)));
typedef float    floatx4 __attribute__((ext_vector_type(4)));

// order-preserving float<->uint encoding for atomicMax
__device__ inline unsigned enc_f(float f) {
    unsigned u = __float_as_uint(f);
    return u ^ (((int)u >> 31) | 0x80000000u);
}
__device__ inline float dec_f(unsigned u) {
    unsigned t = (u & 0x80000000u) ? (u ^ 0x80000000u) : ~u;
    return __uint_as_float(t);
}

// ---- Kernel 1: prep. blocks [0,160): m-side (msq, mT, mh). [160,416): x-side (xh, inits).
__global__ __launch_bounds__(256) void prep_kernel(
        const float* __restrict__ m, const float* __restrict__ x,
        float* __restrict__ msq, float* __restrict__ mT,
        _Float16* __restrict__ mh, _Float16* __restrict__ xh,
        unsigned* __restrict__ smax, int* __restrict__ cnt,
        float* __restrict__ diff_out) {
    __shared__ float tile[64][DIM + 1];
    __shared__ float psum[64][4];
    const int b = blockIdx.x, tid = threadIdx.x;

    if (b < 160) {                              // ---- m part: k0 = b*64
        const int k0 = b * 64;
        const int kl = tid & 63, dg = tid >> 6;
        const int k = k0 + kl;
        float ss = 0.f;
        #pragma unroll 4
        for (int dd = 0; dd < 32; ++dd) {
            int d = dg * 32 + dd;
            float v = (k < K_CLUST) ? m[(size_t)d * K_CLUST + k] : 0.f;
            tile[kl][d] = v;
            ss = fmaf(v, v, ss);
        }
        psum[kl][dg] = ss;
        __syncthreads();
        if (dg == 0)
            msq[k] = (k < K_CLUST) ? (psum[kl][0] + psum[kl][1] + psum[kl][2] + psum[kl][3])
                                   : -1e30f;    // pad never wins
        // mh: [k/16][d/8][k%16][d%8] f16, 16B chunks
        #pragma unroll
        for (int p = 0; p < 4; ++p) {
            int c = tid + p * 256;              // 0..1023
            int kt = c >> 8, dgc = (c >> 4) & 15, k16 = c & 15;
            half8 hv;
            #pragma unroll
            for (int j = 0; j < 8; ++j) hv[j] = (_Float16)tile[kt * 16 + k16][dgc * 8 + j];
            size_t ci = ((size_t)(b * 4 + kt) * 16 + dgc) * 16 + k16;
            ((half8*)mh)[ci] = hv;
        }
        // mT [K,DIM] fp32 for rescue/quant gather
        const int r = tid >> 2, p2 = tid & 3;
        if (k0 + r < K_CLUST) {
            float4* dst = (float4*)(mT + (size_t)(k0 + r) * DIM + p2 * 32);
            #pragma unroll
            for (int j = 0; j < 8; ++j) {
                float4 v;
                v.x = tile[r][p2 * 32 + 4 * j + 0];
                v.y = tile[r][p2 * 32 + 4 * j + 1];
                v.z = tile[r][p2 * 32 + 4 * j + 2];
                v.w = tile[r][p2 * 32 + 4 * j + 3];
                dst[j] = v;
            }
        }
    } else {                                    // ---- x part: s0 = (b-160)*64
        const int s0 = (b - 160) * 64;
        const float4* xg = (const float4*)(x + (size_t)s0 * DIM);
        #pragma unroll
        for (int i = 0; i < 8; ++i) {
            int fi = tid + i * 256;             // 0..2047
            int sl = fi >> 5, d4 = fi & 31;
            float4 v = xg[fi];
            tile[sl][d4 * 4 + 0] = v.x; tile[sl][d4 * 4 + 1] = v.y;
            tile[sl][d4 * 4 + 2] = v.z; tile[sl][d4 * 4 + 3] = v.w;
        }
        __syncthreads();
        // xh: [s/16][d/8][s%16][d%8]
        #pragma unroll
        for (int p = 0; p < 4; ++p) {
            int c = tid + p * 256;
            int st = c >> 8, dgc = (c >> 4) & 15, ml = c & 15;
            half8 hv;
            #pragma unroll
            for (int j = 0; j < 8; ++j) hv[j] = (_Float16)tile[st * 16 + ml][dgc * 8 + j];
            size_t ci = ((size_t)(s0 / 16 + st) * 16 + dgc) * 16 + ml;
            ((half8*)xh)[ci] = hv;
        }
        if (tid < 64) { smax[s0 + tid] = 0u; cnt[s0 + tid] = 0; }
        if (b == 160 && tid == 0) *diff_out = 0.f;
    }
}

// ---- Kernel 2/3: f16 MFMA score pass. COLLECT=false: per-sample max (atomicMax).
//      COLLECT=true: gather candidates with score >= max - MARGIN2.
// Wave owns 64 samples (4 tiles); block's 4 waves share the k-range (B-frags L1-hot).
template <bool COLLECT>
__global__ __launch_bounds__(256, 4) void score_kernel(
        const _Float16* __restrict__ xh, const _Float16* __restrict__ mh,
        const float* __restrict__ msq, unsigned* __restrict__ smax,
        int* __restrict__ cnt, int* __restrict__ cand) {
    const int tid = threadIdx.x;
    const int wv = tid >> 6, lane = tid & 63;
    const int n = lane & 15, quad = lane >> 4;
    const int ks = blockIdx.x & (KSPLIT - 1);
    const int grp = blockIdx.x / KSPLIT;
    const int stile0 = (grp * 4 + wv) * 4;      // 4 sample-tiles per wave
    const int kt0 = ks * KT_PER;

    const half8* xf = (const half8*)xh;
    const half8* mf = (const half8*)mh;

    // A-frags resident across the whole k-loop: 16 x half8 = 64 VGPRs
    half8 a[4][4];
    #pragma unroll
    for (int ii = 0; ii < 4; ++ii)
        #pragma unroll
        for (int t = 0; t < 4; ++t)
            a[ii][t] = xf[((size_t)(stile0 + ii) * 16 + t * 4 + quad) * 16 + n];

    float rmax[4][4];
    float thr[4][4];
    #pragma unroll
    for (int ii = 0; ii < 4; ++ii)
        #pragma unroll
        for (int r = 0; r < 4; ++r) {
            rmax[ii][r] = -FLT_MAX;
            if (COLLECT)
                thr[ii][r] = dec_f(smax[(stile0 + ii) * 16 + quad * 4 + r]) - MARGIN2;
        }

    for (int kt = kt0; kt < kt0 + KT_PER; ++kt) {
        half8 bfr[4];
        #pragma unroll
        for (int t = 0; t < 4; ++t)
            bfr[t] = mf[((size_t)kt * 16 + t * 4 + quad) * 16 + n];
        float mq = msq[kt * 16 + n];
        #pragma unroll
        for (int ii = 0; ii < 4; ++ii) {
            floatx4 c = {0.f, 0.f, 0.f, 0.f};
            #pragma unroll
            for (int t = 0; t < 4; ++t)
                c = __builtin_amdgcn_mfma_f32_16x16x32_f16(a[ii][t], bfr[t], c, 0, 0, 0);
            #pragma unroll
            for (int r = 0; r < 4; ++r) {
                float sc = fmaf(-2.f, c[r], mq);    // score for (row=quad*4+r, col k=kt*16+n)
                if (!COLLECT) {
                    rmax[ii][r] = fmaxf(rmax[ii][r], sc);
                } else if (sc >= thr[ii][r]) {
                    int sample = (stile0 + ii) * 16 + quad * 4 + r;
                    int slot = atomicAdd(&cnt[sample], 1);
                    if (slot < CAP) cand[sample * CAP + slot] = kt * 16 + n;
                }
            }
        }
    }

    if (!COLLECT) {
        #pragma unroll
        for (int ii = 0; ii < 4; ++ii)
            #pragma unroll
            for (int r = 0; r < 4; ++r) {
                float v = rmax[ii][r];
                #pragma unroll
                for (int mk = 1; mk <= 8; mk <<= 1)
                    v = fmaxf(v, __shfl_xor(v, mk));    // reduce over n within quad
                if (n == 0)
                    atomicMax(&smax[(stile0 + ii) * 16 + quad * 4 + r], enc_f(v));
            }
    }
}

// ---- Kernel 4: exact fp32 rescue over candidates; one wave per sample.
__global__ __launch_bounds__(256) void rescue_kernel(
        const float* __restrict__ x, const float* __restrict__ mT,
        const float* __restrict__ msq, const int* __restrict__ cnt,
        const int* __restrict__ cand, int* __restrict__ idx_i,
        float* __restrict__ idx_f) {
    const int wv = threadIdx.x >> 6, lane = threadIdx.x & 63;
    const int s = blockIdx.x * 4 + wv;
    const float2 xx = ((const float2*)x)[(size_t)s * 64 + lane];
    const int c = cnt[s];
    float best = -FLT_MAX; int bk = 0x7fffffff;
    if (c <= CAP) {
        for (int i = 0; i < c; ++i) {
            int k = cand[s * CAP + i];
            float2 mm = ((const float2*)mT)[(size_t)k * 64 + lane];
            float p = xx.x * mm.x + xx.y * mm.y;
            #pragma unroll
            for (int off = 32; off; off >>= 1) p += __shfl_xor(p, off);
            float sc = msq[k] - 2.f * p;
            if (sc > best || (sc == best && k < bk)) { best = sc; bk = k; }
        }
    } else {                                    // overflow: exact full scan (never expected)
        for (int k = 0; k < K_CLUST; ++k) {
            float2 mm = ((const float2*)mT)[(size_t)k * 64 + lane];
            float p = xx.x * mm.x + xx.y * mm.y;
            #pragma unroll
            for (int off = 32; off; off >>= 1) p += __shfl_xor(p, off);
            float sc = msq[k] - 2.f * p;
            if (sc > best) { best = sc; bk = k; }   // ascending k: '>' keeps lowest
        }
    }
    if (lane == 0) { idx_i[s] = bk; idx_f[s] = (float)bk; }
}

// ---- Kernel 5: gather quantize (coalesced via mT), MSE.
__global__ void quant_kernel(const float* __restrict__ x, const float* __restrict__ mT,
                             const int* __restrict__ idx_i, float* __restrict__ qout,
                             float* __restrict__ diff_out) {
    int g = blockIdx.x * 256 + threadIdx.x;     // one thread per (sample, d4)
    int samp = g >> 5;
    int d4   = g & 31;
    int idx  = idx_i[samp];
    float4 q  = ((const float4*)mT)[(size_t)idx * (DIM / 4) + d4];
    float4 xv = ((const float4*)x)[g];
    ((float4*)qout)[g] = q;
    float ax = xv.x - q.x, ay = xv.y - q.y, az = xv.z - q.z, aw = xv.w - q.w;
    float dd = ax * ax + ay * ay + az * az + aw * aw;
    #pragma unroll
    for (int off = 32; off; off >>= 1) dd += __shfl_down(dd, off);
    __shared__ float wsum[4];
    int lane = threadIdx.x & 63, wv = threadIdx.x >> 6;
    if (lane == 0) wsum[wv] = dd;
    __syncthreads();
    if (threadIdx.x == 0) {
        float t = wsum[0] + wsum[1] + wsum[2] + wsum[3];
        atomicAdd(diff_out, t * (1.0f / ((float)N_SAMP * (float)DIM)));
    }
}

extern "C" void kernel_launch(void* const* d_in, const int* in_sizes, int n_in,
                              void* d_out, int out_size, void* d_ws, size_t ws_size,
                              hipStream_t stream) {
    const float* x = (const float*)d_in[0];          // [16,32,32,128]
    const float* m = (const float*)d_in[1];          // [128,10000]
    float* out    = (float*)d_out;
    float* quant  = out;                                  // 2,097,152 f
    float* idx_f  = out + (size_t)N_SAMP * DIM;           // 16,384 f
    float* diff   = out + (size_t)N_SAMP * DIM + N_SAMP;  // 1 f

    char* ws = (char*)d_ws;                  // ~13.2 MB total
    float*     msq  = (float*)    (ws);                       // 10240 f  (40,960 B)
    float*     mT   = (float*)    (ws + 40960);               // 10000*128 f (5,120,000 B)
    _Float16*  mh   = (_Float16*) (ws + 5160960);             // 10240*128 h (2,621,440 B)
    _Float16*  xh   = (_Float16*) (ws + 7782400);             // 16384*128 h (4,194,304 B)
    unsigned*  smax = (unsigned*) (ws + 11976704);            // 16384 u
    int*       cnt  = (int*)      (ws + 12042240);            // 16384 i
    int*       cand = (int*)      (ws + 12107776);            // 16384*CAP i (1,048,576 B)
    int*       idx_i = cnt + 0;   // reuse? no — keep separate:
    idx_i = (int*)(ws + 13156352);                            // 16384 i

    prep_kernel<<<416, 256, 0, stream>>>(m, x, msq, mT, mh, xh, smax, cnt, diff);
    score_kernel<false><<<64 * KSPLIT, 256, 0, stream>>>(xh, mh, msq, smax, cnt, cand);
    score_kernel<true><<<64 * KSPLIT, 256, 0, stream>>>(xh, mh, msq, smax, cnt, cand);
    rescue_kernel<<<N_SAMP / 4, 256, 0, stream>>>(x, mT, msq, cnt, cand, idx_i, idx_f);
    quant_kernel<<<(N_SAMP * DIM / 4) / 256, 256, 0, stream>>>(x, mT, idx_i, quant, diff);
}